// Round 10
// baseline (269.117 us; speedup 1.0000x reference)
//
#include <hip/hip_runtime.h>

typedef __attribute__((ext_vector_type(4))) float f32x4;
typedef __attribute__((ext_vector_type(8))) _Float16 f16x8;
typedef __attribute__((ext_vector_type(4))) _Float16 f16x4;

#define D 256          // D_in == D_out == 256
#define VBS 128        // ghost batch rows per chunk
#define BN_EPS 1e-5f

// ---------------------------------------------------------------- pack W
// Pack W[k][n] (f32, row-major 256x256) into f16 MFMA fragment order.
// frag value = W[kb*32+(l>>4)*8+j][ct*16+(l&15)], frag (kb,ct,lane) at
// wp + ((kb*16+ct)*64+lane)*8.
__global__ void pack_w_kernel(const float* __restrict__ W, _Float16* __restrict__ wp) {
    int idx = blockIdx.x * blockDim.x + threadIdx.x;   // [0, 8192)
    int kb  = idx >> 10;
    int rem = idx & 1023;
    int ct  = rem >> 6;
    int l   = rem & 63;
    int col = ct * 16 + (l & 15);
    int k0  = kb * 32 + ((l >> 4) << 3);
    f16x8 v;
#pragma unroll
    for (int j = 0; j < 8; ++j) v[j] = (_Float16)W[(k0 + j) * D + col];
    *reinterpret_cast<f16x8*>(wp + (size_t)idx * 8) = v;
}

// 16-lane (DPP row) all-lanes sum: VALU pipe only.
template <int CTRL>
__device__ __forceinline__ float row_ror_add(float x) {
    int v = __builtin_amdgcn_update_dpp(0, __builtin_bit_cast(int, x),
                                        CTRL, 0xF, 0xF, true);
    return x + __builtin_bit_cast(float, v);
}
__device__ __forceinline__ float rsum16(float x) {
    x = row_ror_add<0x128>(x);
    x = row_ror_add<0x124>(x);
    x = row_ror_add<0x122>(x);
    x = row_ror_add<0x121>(x);
    return x;
}

#define GLL16(g, l)                                                     \
    __builtin_amdgcn_global_load_lds(                                   \
        (const __attribute__((address_space(1))) unsigned*)(g),         \
        (__attribute__((address_space(3))) unsigned*)(l), 16, 0, 0)

// LDS map (bytes):
//   GEMM phase:  [0,16384) Wbuf0 | [16384,32768) Wbuf1
//                [32768,49152) abuf0 (half0 8K | half1 8K) | [49152,65536) abuf1
//   epilogue:    [0,67584) h tile: 128 rows x 264 f16 (8-f16 pad)  [overlays bufs]
//   stats:       [67584,75776) sSum[8][256] | [75776,83968) sSq
//                [83968,84992) sA | [84992,86016) sB
#define H_STRIDE 264

// One block per BN chunk; 1024 threads = 16 waves = 8 row-strips x 2 col-halves.
// TRANSPOSED mfma: wave (rs,cg): acc[ct] holds rows rs*16+(lane&15),
// cols cg*128 + ct*16 + (lane>>4)*4 + {0..3}.  acc = 32 VGPR/thread.
__global__ __launch_bounds__(1024, 4)
void fused_kernel(const float* __restrict__ A, const float* __restrict__ priors,
                  const _Float16* __restrict__ Wp, const float* __restrict__ gamma,
                  const float* __restrict__ beta, float* __restrict__ out) {
    const int tid  = threadIdx.x;
    const int lane = tid & 63;
    const int wid  = tid >> 6;     // 0..15
    const int lrow = lane & 15;
    const int q    = lane >> 4;
    const int rs   = wid >> 1;     // row strip (16 rows)
    const int cg   = wid & 1;      // col half (128 cols)
    const int chunk = blockIdx.x;

    __shared__ char smem[86016];

    f32x4 acc[8];
#pragma unroll
    for (int ct = 0; ct < 8; ++ct) { f32x4 z = {0.f, 0.f, 0.f, 0.f}; acc[ct] = z; }

    // ---- staging addresses ----
    const char* wsrc = (const char*)Wp + (size_t)tid * 16;   // + kb*16384
    const int slot = tid & 511;        // 32-B a-frag index (rs_t*64 + lane_t)
    const int pc   = tid >> 9;         // which 16-B half of the frag
    const int a_row  = chunk * VBS + ((slot >> 6) << 4) + (slot & 15);
    const int a_kofs = ((slot & 63) >> 4) * 8 + pc * 4;
    const char* asrc = (const char*)(A + (size_t)a_row * D + a_kofs);  // + kb*128
    char* wdst = smem + (size_t)tid * 16;                         // + p*16384
    char* adst = smem + 32768 + pc * 8192 + (size_t)slot * 16;    // + p*16384

    // prologue: stage slab 0
    GLL16(wsrc, wdst);
    GLL16(asrc, adst);
    __syncthreads();

    const int a_off = (rs * 64 + lane) * 16;              // byte in a-half region
    const int w_off = ((cg * 8) * 64 + lane) * 16;        // first of my 8 W frags

#pragma unroll 1
    for (int kb = 0; kb < 8; ++kb) {
        const int p = kb & 1;
        if (kb < 7) {
            const int np = p ^ 1;
            GLL16(wsrc + (size_t)(kb + 1) * 16384, wdst + np * 16384);
            GLL16(asrc + (size_t)(kb + 1) * 128,   adst + np * 16384);
        }
        const char* ab = smem + 32768 + p * 16384;
        f32x4 alo = *reinterpret_cast<const f32x4*>(ab + a_off);
        f32x4 ahi = *reinterpret_cast<const f32x4*>(ab + 8192 + a_off);
        f16x8 t;
#pragma unroll
        for (int j = 0; j < 4; ++j) { t[j] = (_Float16)alo[j]; t[j + 4] = (_Float16)ahi[j]; }
        const char* wb = smem + p * 16384 + w_off;
#pragma unroll
        for (int g = 0; g < 2; ++g) {
            f16x8 w0 = *reinterpret_cast<const f16x8*>(wb + (g * 4 + 0) * 1024);
            f16x8 w1 = *reinterpret_cast<const f16x8*>(wb + (g * 4 + 1) * 1024);
            f16x8 w2 = *reinterpret_cast<const f16x8*>(wb + (g * 4 + 2) * 1024);
            f16x8 w3 = *reinterpret_cast<const f16x8*>(wb + (g * 4 + 3) * 1024);
            acc[g * 4 + 0] = __builtin_amdgcn_mfma_f32_16x16x32_f16(w0, t, acc[g * 4 + 0], 0, 0, 0);
            acc[g * 4 + 1] = __builtin_amdgcn_mfma_f32_16x16x32_f16(w1, t, acc[g * 4 + 1], 0, 0, 0);
            acc[g * 4 + 2] = __builtin_amdgcn_mfma_f32_16x16x32_f16(w2, t, acc[g * 4 + 2], 0, 0, 0);
            acc[g * 4 + 3] = __builtin_amdgcn_mfma_f32_16x16x32_f16(w3, t, acc[g * 4 + 3], 0, 0, 0);
        }
        __syncthreads();   // sW/sa[p] reads done; next stage drained
    }

    // ---- stats (DPP rsum over 16 rows of the strip) + h -> LDS (f16) ----
    float* sSum = (float*)(smem + 67584);
    float* sSq  = (float*)(smem + 75776);
    float* sA   = (float*)(smem + 83968);
    float* sB   = (float*)(smem + 84992);
    _Float16* hl = (_Float16*)smem;
    const int hrow0 = rs * 16 + lrow;
#pragma unroll
    for (int ct = 0; ct < 8; ++ct) {
        f32x4 s = acc[ct];
        f32x4 qv = s * s;
#pragma unroll
        for (int c = 0; c < 4; ++c) { s[c] = rsum16(s[c]); qv[c] = rsum16(qv[c]); }
        const int col = cg * 128 + ct * 16 + q * 4;
        if (lrow == 0) {
            *reinterpret_cast<f32x4*>(&sSum[rs * D + col]) = s;
            *reinterpret_cast<f32x4*>(&sSq [rs * D + col]) = qv;
        }
        f16x4 hv;
#pragma unroll
        for (int k = 0; k < 4; ++k) hv[k] = (_Float16)acc[ct][k];
        *reinterpret_cast<f16x4*>(hl + hrow0 * H_STRIDE + col) = hv;
    }
    __syncthreads();

    if (tid < D) {
        float s = 0.f, qq = 0.f;
#pragma unroll
        for (int w = 0; w < 8; ++w) { s += sSum[w * D + tid]; qq += sSq[w * D + tid]; }
        float mean = s * (1.0f / 128.0f);
        float var  = qq * (1.0f / 128.0f) - mean * mean;
        float g    = gamma[tid] * rsqrtf(var + BN_EPS);
        sA[tid] = g;
        sB[tid] = beta[tid] - mean * g;
    }
    __syncthreads();

    // ---- epilogue: 8 threads per row, 32 cols each; tau shfl-local ----
    const int erow = tid >> 3;        // 0..127
    const int cb   = tid & 7;         // 32-col block
    const int grow = chunk * VBS + erow;
    const _Float16* hp = hl + erow * H_STRIDE + cb * 32;
    const float* pr = priors + (size_t)grow * D + cb * 32;

    f32x4 z[8];
    float m = -1e30f;
#pragma unroll
    for (int i = 0; i < 4; ++i) {
        f16x8 hv = *reinterpret_cast<const f16x8*>(hp + i * 8);
        f32x4 ga0 = *reinterpret_cast<const f32x4*>(&sA[cb * 32 + i * 8]);
        f32x4 ga1 = *reinterpret_cast<const f32x4*>(&sA[cb * 32 + i * 8 + 4]);
        f32x4 gb0 = *reinterpret_cast<const f32x4*>(&sB[cb * 32 + i * 8]);
        f32x4 gb1 = *reinterpret_cast<const f32x4*>(&sB[cb * 32 + i * 8 + 4]);
        f32x4 p0  = *reinterpret_cast<const f32x4*>(pr + i * 8);
        f32x4 p1  = *reinterpret_cast<const f32x4*>(pr + i * 8 + 4);
        f32x4 x0, x1;
#pragma unroll
        for (int j = 0; j < 4; ++j) {
            x0[j] = ((float)hv[j]     * ga0[j] + gb0[j]) * p0[j];
            x1[j] = ((float)hv[j + 4] * ga1[j] + gb1[j]) * p1[j];
        }
        z[i * 2] = x0;
        z[i * 2 + 1] = x1;
#pragma unroll
        for (int j = 0; j < 4; ++j) m = fmaxf(m, fmaxf(x0[j], x1[j]));
    }
    m = fmaxf(m, __shfl_xor(m, 1));
    m = fmaxf(m, __shfl_xor(m, 2));
    m = fmaxf(m, __shfl_xor(m, 4));

    // Michelot fixed-point from tau0 = m-1 (monotone to the exact root).
    float tau = m - 1.0f;
#pragma unroll 1
    for (int it = 0; it < 32; ++it) {
        float s = 0.f, c = 0.f;
#pragma unroll
        for (int i = 0; i < 8; ++i)
#pragma unroll
            for (int k = 0; k < 4; ++k) {
                float zz = z[i][k];
                if (zz > tau) { s += zz; c += 1.f; }
            }
        s += __shfl_xor(s, 1); c += __shfl_xor(c, 1);
        s += __shfl_xor(s, 2); c += __shfl_xor(c, 2);
        s += __shfl_xor(s, 4); c += __shfl_xor(c, 4);
        float n = (s - 1.0f) / c;
        bool done = (n <= tau);
        tau = fmaxf(tau, n);
        if (__all(done)) break;
    }

    float* ob = out + (size_t)grow * D + cb * 32;
#pragma unroll
    for (int i = 0; i < 8; ++i) {
        f32x4 r;
#pragma unroll
        for (int k = 0; k < 4; ++k) r[k] = fmaxf(z[i][k] - tau, 0.f);
        *reinterpret_cast<f32x4*>(ob + i * 4) = r;
    }
}

extern "C" void kernel_launch(void* const* d_in, const int* in_sizes, int n_in,
                              void* d_out, int out_size, void* d_ws, size_t ws_size,
                              hipStream_t stream) {
    const float* a      = (const float*)d_in[0];
    const float* priors = (const float*)d_in[1];
    const float* W      = (const float*)d_in[2];
    // d_in[3] = b : unused — ghost-BN mean subtraction cancels any per-column bias.
    const float* gamma  = (const float*)d_in[4];
    const float* beta   = (const float*)d_in[5];
    float* out = (float*)d_out;
    _Float16* wp = (_Float16*)d_ws;   // 256*256 f16 = 128 KB packed W

    const int B = in_sizes[0] / D;        // 262144
    const int nchunks = B / VBS;          // 2048

    hipLaunchKernelGGL(pack_w_kernel, dim3(32), dim3(256), 0, stream, W, wp);
    hipLaunchKernelGGL(fused_kernel, dim3(nchunks), dim3(1024), 0, stream,
                       a, priors, wp, gamma, beta, out);
}

// Round 11
// 214.185 us; speedup vs baseline: 1.2565x; 1.2565x over previous
//
#include <hip/hip_runtime.h>

typedef __attribute__((ext_vector_type(4))) float f32x4;
typedef __attribute__((ext_vector_type(8))) _Float16 f16x8;

#define D 256          // D_in == D_out == 256
#define VBS 128        // ghost batch rows per chunk
#define BN_EPS 1e-5f

// ---------------------------------------------------------------- pack W
// Pack W[k][n] (f32, row-major 256x256) into f16 MFMA fragment order.
// frag value = W[kb*32+(l>>4)*8+j][ct*16+(l&15)], frag (kb,ct,lane) at
// wp + ((kb*16+ct)*64+lane)*8.
__global__ void pack_w_kernel(const float* __restrict__ W, _Float16* __restrict__ wp) {
    int idx = blockIdx.x * blockDim.x + threadIdx.x;   // [0, 8192)
    int kb  = idx >> 10;
    int rem = idx & 1023;
    int ct  = rem >> 6;
    int l   = rem & 63;
    int col = ct * 16 + (l & 15);
    int k0  = kb * 32 + ((l >> 4) << 3);
    f16x8 v;
#pragma unroll
    for (int j = 0; j < 8; ++j) v[j] = (_Float16)W[(k0 + j) * D + col];
    *reinterpret_cast<f16x8*>(wp + (size_t)idx * 8) = v;
}

// 16-lane (DPP row) all-lanes sum: VALU pipe only.
template <int CTRL>
__device__ __forceinline__ float row_ror_add(float x) {
    int v = __builtin_amdgcn_update_dpp(0, __builtin_bit_cast(int, x),
                                        CTRL, 0xF, 0xF, true);
    return x + __builtin_bit_cast(float, v);
}
__device__ __forceinline__ float rsum16(float x) {
    x = row_ror_add<0x128>(x);
    x = row_ror_add<0x124>(x);
    x = row_ror_add<0x122>(x);
    x = row_ror_add<0x121>(x);
    return x;
}

#define GLL16(g, l)                                                     \
    __builtin_amdgcn_global_load_lds(                                   \
        (const __attribute__((address_space(1))) unsigned*)(g),         \
        (__attribute__((address_space(3))) unsigned*)(l), 16, 0, 0)

// LDS map (bytes):
//   [0,49152)       W slabs, 3 x 16 KB        (slab kb at (kb%3)*16384)
//   [49152,98304)   a slabs, 3 x 16 KB, each = {half0 8 KB | half1 8 KB}
//   [98304,106496)  sSum[8][256]   [106496,114688) sSq
//   [114688,115712) sA             [115712,116736) sB
//
// One block per BN chunk (128 rows); 8 waves x 16 rows; h stays in acc regs.
// TRANSPOSED mfma: acc[ct] = mfma(W^T-frag, a-frag); lane holds row
// (chunk*128 + wid*16 + (lane&15)), cols ct*16 + (lane>>4)*4 + {0..3}.
//
// K-loop: 3-deep LDS pipeline. stage(kb+2) issued while computing kb;
// counted s_waitcnt vmcnt(4) + RAW s_barrier per step -> one slab (4 GLL)
// always in flight across the barrier (T3/T4: never drain vmcnt to 0).
__global__ __launch_bounds__(512, 2)
void fused_kernel(const float* __restrict__ A, const float* __restrict__ priors,
                  const _Float16* __restrict__ Wp, const float* __restrict__ gamma,
                  const float* __restrict__ beta, float* __restrict__ out) {
    const int tid  = threadIdx.x;
    const int wid  = tid >> 6;    // 0..7
    const int lane = tid & 63;
    const int lrow = lane & 15;
    const int q    = lane >> 4;
    const int chunk = blockIdx.x;
    const int myrow = chunk * VBS + wid * 16 + lrow;

    __shared__ char smem[116736];

    f32x4 acc[16];
#pragma unroll
    for (int ct = 0; ct < 16; ++ct) { f32x4 z = {0.f, 0.f, 0.f, 0.f}; acc[ct] = z; }

    // ---- staging addresses (thread tid owns a-frag slot tid) ----
    const char* wsrc = (const char*)Wp + (size_t)tid * 16;   // + kb*16384 (+8192)
    const int arow = chunk * VBS + ((tid >> 6) << 4) + (tid & 15);
    const int akof = ((tid & 63) >> 4) * 8;                  // k offset (floats)
    const char* asrc = (const char*)(A + (size_t)arow * D + akof);  // + kb*128
    char* wdst = smem + (size_t)tid * 16;                    // + buf*16384
    char* adst = smem + 49152 + (size_t)tid * 16;            // + buf*16384 (+8192)

#define STAGE(kb, buf)                                                   \
    do {                                                                 \
        const char* _w = wsrc + (size_t)(kb) * 16384;                    \
        char* _wd = wdst + (buf) * 16384;                                \
        GLL16(_w, _wd);                                                  \
        GLL16(_w + 8192, _wd + 8192);                                    \
        const char* _a = asrc + (size_t)(kb) * 128;                      \
        char* _ad = adst + (buf) * 16384;                                \
        GLL16(_a, _ad);          /* half0: floats k0..k0+3  */           \
        GLL16(_a + 16, _ad + 8192); /* half1: floats k0+4..k0+7 */       \
    } while (0)

    // prologue: 2 slabs in flight, wait only for slab 0 (vmcnt 8 -> 4)
    STAGE(0, 0);
    STAGE(1, 1);
    asm volatile("s_waitcnt vmcnt(4)" ::: "memory");
    __builtin_amdgcn_s_barrier();

    int cur = 0;
#pragma unroll 1
    for (int kb = 0; kb < 8; ++kb) {
        if (kb < 6) {
            int b2 = cur + 2; if (b2 >= 3) b2 -= 3;
            STAGE(kb + 2, b2);
        }
        // a fragment: contiguous 16 B/lane per half (conflict-free b128)
        const char* ab = smem + 49152 + cur * 16384;
        f32x4 alo = *reinterpret_cast<const f32x4*>(ab + tid * 16);
        f32x4 ahi = *reinterpret_cast<const f32x4*>(ab + 8192 + tid * 16);
        f16x8 t;
#pragma unroll
        for (int j = 0; j < 4; ++j) { t[j] = (_Float16)alo[j]; t[j + 4] = (_Float16)ahi[j]; }
        const char* wb = smem + cur * 16384 + lane * 16;
#pragma unroll
        for (int g = 0; g < 4; ++g) {
            f16x8 w0 = *reinterpret_cast<const f16x8*>(wb + (g * 4 + 0) * 1024);
            f16x8 w1 = *reinterpret_cast<const f16x8*>(wb + (g * 4 + 1) * 1024);
            f16x8 w2 = *reinterpret_cast<const f16x8*>(wb + (g * 4 + 2) * 1024);
            f16x8 w3 = *reinterpret_cast<const f16x8*>(wb + (g * 4 + 3) * 1024);
            acc[g * 4 + 0] = __builtin_amdgcn_mfma_f32_16x16x32_f16(w0, t, acc[g * 4 + 0], 0, 0, 0);
            acc[g * 4 + 1] = __builtin_amdgcn_mfma_f32_16x16x32_f16(w1, t, acc[g * 4 + 1], 0, 0, 0);
            acc[g * 4 + 2] = __builtin_amdgcn_mfma_f32_16x16x32_f16(w2, t, acc[g * 4 + 2], 0, 0, 0);
            acc[g * 4 + 3] = __builtin_amdgcn_mfma_f32_16x16x32_f16(w3, t, acc[g * 4 + 3], 0, 0, 0);
        }
        // counted wait: oldest in-flight slab (kb+1) arrived; slab kb+2 stays in flight
        if (kb < 6)       asm volatile("s_waitcnt vmcnt(4)" ::: "memory");
        else if (kb == 6) asm volatile("s_waitcnt vmcnt(0)" ::: "memory");
        if (kb < 7) __builtin_amdgcn_s_barrier();
        cur = (cur == 2) ? 0 : cur + 1;
    }
#undef STAGE

    // ---- priors early-issue (T14): fly during the stats phase ----
    const float* pr = priors + (size_t)myrow * D;
    f32x4 p[16];
#pragma unroll
    for (int ct = 0; ct < 16; ++ct)
        p[ct] = *reinterpret_cast<const f32x4*>(pr + ct * 16 + q * 4);

    // ---- Ghost BN stats (DPP rsum16 per strip; cross-wave via LDS) ----
    float* sSum = (float*)(smem + 98304);
    float* sSq  = (float*)(smem + 106496);
    float* sA   = (float*)(smem + 114688);
    float* sB   = (float*)(smem + 115712);
#pragma unroll
    for (int ct = 0; ct < 16; ++ct) {
        f32x4 s = acc[ct];
        f32x4 qv = s * s;
#pragma unroll
        for (int c = 0; c < 4; ++c) { s[c] = rsum16(s[c]); qv[c] = rsum16(qv[c]); }
        if (lrow == 0) {
            *reinterpret_cast<f32x4*>(&sSum[wid * D + ct * 16 + q * 4]) = s;
            *reinterpret_cast<f32x4*>(&sSq [wid * D + ct * 16 + q * 4]) = qv;
        }
    }
    __syncthreads();
    if (tid < D) {
        float s = 0.f, qq = 0.f;
#pragma unroll
        for (int w = 0; w < 8; ++w) { s += sSum[w * D + tid]; qq += sSq[w * D + tid]; }
        float mean = s * (1.0f / 128.0f);
        float var  = qq * (1.0f / 128.0f) - mean * mean;
        float g    = gamma[tid] * rsqrtf(var + BN_EPS);
        sA[tid] = g;
        sB[tid] = beta[tid] - mean * g;
    }
    __syncthreads();

    // ---- epilogue: BN apply, * priors, sparsemax (one row per lrow-lane) ----
    float m = -1e30f;
#pragma unroll
    for (int ct = 0; ct < 16; ++ct) {
        int c0 = ct * 16 + q * 4;
        f32x4 ga = *reinterpret_cast<const f32x4*>(&sA[c0]);
        f32x4 bb = *reinterpret_cast<const f32x4*>(&sB[c0]);
        f32x4 x  = (acc[ct] * ga + bb) * p[ct];
        acc[ct] = x;
        m = fmaxf(m, fmaxf(fmaxf(x[0], x[1]), fmaxf(x[2], x[3])));
    }
    m = fmaxf(m, __shfl_xor(m, 16));
    m = fmaxf(m, __shfl_xor(m, 32));

    // Michelot fixed-point from tau0 = m-1 (monotone to the exact root).
    float tau = m - 1.0f;
#pragma unroll 1
    for (int it = 0; it < 32; ++it) {
        float s = 0.f, c = 0.f;
#pragma unroll
        for (int ct = 0; ct < 16; ++ct)
#pragma unroll
            for (int k = 0; k < 4; ++k) {
                float zz = acc[ct][k];
                if (zz > tau) { s += zz; c += 1.f; }
            }
        s += __shfl_xor(s, 16); c += __shfl_xor(c, 16);
        s += __shfl_xor(s, 32); c += __shfl_xor(c, 32);
        float n = (s - 1.0f) / c;
        bool done = (n <= tau);
        tau = fmaxf(tau, n);
        if (__all(done)) break;
    }

    float* ob = out + (size_t)myrow * D;
#pragma unroll
    for (int ct = 0; ct < 16; ++ct) {
        int c0 = ct * 16 + q * 4;
        f32x4 x = acc[ct];
        f32x4 r;
#pragma unroll
        for (int k = 0; k < 4; ++k) r[k] = fmaxf(x[k] - tau, 0.f);
        *reinterpret_cast<f32x4*>(&ob[c0]) = r;
    }
}

extern "C" void kernel_launch(void* const* d_in, const int* in_sizes, int n_in,
                              void* d_out, int out_size, void* d_ws, size_t ws_size,
                              hipStream_t stream) {
    const float* a      = (const float*)d_in[0];
    const float* priors = (const float*)d_in[1];
    const float* W      = (const float*)d_in[2];
    // d_in[3] = b : unused — ghost-BN mean subtraction cancels any per-column bias.
    const float* gamma  = (const float*)d_in[4];
    const float* beta   = (const float*)d_in[5];
    float* out = (float*)d_out;
    _Float16* wp = (_Float16*)d_ws;   // 256*256 f16 = 128 KB packed W

    const int B = in_sizes[0] / D;        // 262144
    const int nchunks = B / VBS;          // 2048

    hipLaunchKernelGGL(pack_w_kernel, dim3(32), dim3(256), 0, stream, W, wp);
    hipLaunchKernelGGL(fused_kernel, dim3(nchunks), dim3(512), 0, stream,
                       a, priors, wp, gamma, beta, out);
}

// Round 12
// 211.020 us; speedup vs baseline: 1.2753x; 1.0150x over previous
//
#include <hip/hip_runtime.h>

typedef __attribute__((ext_vector_type(4))) float f32x4;
typedef __attribute__((ext_vector_type(8))) _Float16 f16x8;

#define D 256          // D_in == D_out == 256
#define VBS 128        // ghost batch rows per chunk
#define BN_EPS 1e-5f

// ---------------------------------------------------------------- pack W
// Pack W[k][n] (f32, row-major 256x256) into f16 MFMA fragment order.
// frag value = W[kb*32+(l>>4)*8+j][ct*16+(l&15)], frag (kb,ct,lane) at
// wp + ((kb*16+ct)*64+lane)*8.
__global__ void pack_w_kernel(const float* __restrict__ W, _Float16* __restrict__ wp) {
    int idx = blockIdx.x * blockDim.x + threadIdx.x;   // [0, 8192)
    int kb  = idx >> 10;
    int rem = idx & 1023;
    int ct  = rem >> 6;
    int l   = rem & 63;
    int col = ct * 16 + (l & 15);
    int k0  = kb * 32 + ((l >> 4) << 3);
    f16x8 v;
#pragma unroll
    for (int j = 0; j < 8; ++j) v[j] = (_Float16)W[(k0 + j) * D + col];
    *reinterpret_cast<f16x8*>(wp + (size_t)idx * 8) = v;
}

// 16-lane (DPP row) all-lanes sum: VALU pipe only.
template <int CTRL>
__device__ __forceinline__ float row_ror_add(float x) {
    int v = __builtin_amdgcn_update_dpp(0, __builtin_bit_cast(int, x),
                                        CTRL, 0xF, 0xF, true);
    return x + __builtin_bit_cast(float, v);
}
__device__ __forceinline__ float rsum16(float x) {
    x = row_ror_add<0x128>(x);
    x = row_ror_add<0x124>(x);
    x = row_ror_add<0x122>(x);
    x = row_ror_add<0x121>(x);
    return x;
}

#define GLL16(g, l)                                                     \
    __builtin_amdgcn_global_load_lds(                                   \
        (const __attribute__((address_space(1))) unsigned*)(g),         \
        (__attribute__((address_space(3))) unsigned*)(l), 16, 0, 0)

// LDS map (bytes):
//   [0,49152)       W slabs, 3 x 16 KB ring
//   [49152,98304)   a slabs, 3 x 16 KB ring, each = {half0 8 KB | half1 8 KB}
//   [98304,106496)  sSum[8][256]   [106496,114688) sSq
//   [114688,115712) sA             [115712,116736) sB
//
// PERSISTENT blocks: grid=256 (1/CU), each block processes `iters` chunks.
// The 3-slab ring + counted vmcnt(4) discipline continues ACROSS chunk
// boundaries (kb=6,7 stage next chunk's slabs 0,1), so HBM stays loaded
// while the epilogue (stats/sparsemax, VALU+LDS only) runs. Epilogue
// barriers are raw s_barrier + lgkmcnt-only waits: in-flight slab GLLs
// are never drained (T4: no vmcnt(0) in the steady-state loop).
__global__ __launch_bounds__(512, 2)
void fused_kernel(const float* __restrict__ A, const float* __restrict__ priors,
                  const _Float16* __restrict__ Wp, const float* __restrict__ gamma,
                  const float* __restrict__ beta, float* __restrict__ out, int iters) {
    const int tid  = threadIdx.x;
    const int wid  = tid >> 6;    // 0..7
    const int lane = tid & 63;
    const int lrow = lane & 15;
    const int q    = lane >> 4;

    __shared__ char smem[116736];

    // ---- staging addresses (thread tid owns a-frag slot tid) ----
    const char* wsrc = (const char*)Wp + (size_t)tid * 16;   // + kb*16384 (+8192)
    char* wdst = smem + (size_t)tid * 16;                    // + buf*16384
    char* adst = smem + 49152 + (size_t)tid * 16;            // + buf*16384 (+8192)
    const int rowoff = ((tid >> 6) << 4) + (tid & 15);
    const int akofB  = (((tid & 63) >> 4) * 8) * 4;          // k-offset bytes

    const int  c0 = blockIdx.x;
    const int  GRID = gridDim.x;
    const char* aA = (const char*)A + ((size_t)(c0 * VBS + rowoff) * D) * 4 + akofB;
    const size_t CSTRIDE = (size_t)GRID * VBS * D * 4;

#define STAGE_WK(kb, buf)                                                \
    do {                                                                 \
        const char* _w = wsrc + (size_t)(kb) * 16384;                    \
        char* _wd = wdst + (buf) * 16384;                                \
        GLL16(_w, _wd);                                                  \
        GLL16(_w + 8192, _wd + 8192);                                    \
    } while (0)
#define STAGE_AK(abase, kb, buf)                                         \
    do {                                                                 \
        const char* _a = (abase) + (size_t)(kb) * 128;                   \
        char* _ad = adst + (buf) * 16384;                                \
        GLL16(_a, _ad);              /* half0: floats k0..k0+3  */       \
        GLL16(_a + 16, _ad + 8192);  /* half1: floats k0+4..k0+7 */      \
    } while (0)

    float* sSum = (float*)(smem + 98304);
    float* sSq  = (float*)(smem + 106496);
    float* sA   = (float*)(smem + 114688);
    float* sB   = (float*)(smem + 115712);

    // prologue: stage slabs 0,1 of first chunk; wait slab 0 (8 -> 4 in flight)
    STAGE_WK(0, 0); STAGE_AK(aA, 0, 0);
    STAGE_WK(1, 1); STAGE_AK(aA, 1, 1);
    asm volatile("s_waitcnt vmcnt(4)" ::: "memory");
    __builtin_amdgcn_s_barrier();
    asm volatile("" ::: "memory");

    int bufc = 0;   // buffer of the slab being computed
    int bufs = 2;   // buffer for the next staged slab

#pragma unroll 1
    for (int it = 0; it < iters; ++it) {
        const int myrow = (c0 + it * GRID) * VBS + wid * 16 + lrow;
        const char* aN = aA + CSTRIDE;
        const bool lastc = (it == iters - 1);

        f32x4 acc[16];
#pragma unroll
        for (int ct = 0; ct < 16; ++ct) { f32x4 z = {0.f, 0.f, 0.f, 0.f}; acc[ct] = z; }

#pragma unroll 1
        for (int kb = 0; kb < 8; ++kb) {
            bool more = false;
            if (kb < 6)      { STAGE_WK(kb + 2, bufs); STAGE_AK(aA, kb + 2, bufs); more = true; }
            else if (!lastc) { STAGE_WK(kb - 6, bufs); STAGE_AK(aN, kb - 6, bufs); more = true; }

            // a fragment: contiguous 16 B/lane per half (conflict-free b128)
            const char* ab = smem + 49152 + bufc * 16384;
            f32x4 alo = *reinterpret_cast<const f32x4*>(ab + tid * 16);
            f32x4 ahi = *reinterpret_cast<const f32x4*>(ab + 8192 + tid * 16);
            f16x8 t;
#pragma unroll
            for (int j = 0; j < 4; ++j) { t[j] = (_Float16)alo[j]; t[j + 4] = (_Float16)ahi[j]; }
            const char* wb = smem + bufc * 16384 + lane * 16;
#pragma unroll
            for (int g = 0; g < 4; ++g) {
                f16x8 w0 = *reinterpret_cast<const f16x8*>(wb + (g * 4 + 0) * 1024);
                f16x8 w1 = *reinterpret_cast<const f16x8*>(wb + (g * 4 + 1) * 1024);
                f16x8 w2 = *reinterpret_cast<const f16x8*>(wb + (g * 4 + 2) * 1024);
                f16x8 w3 = *reinterpret_cast<const f16x8*>(wb + (g * 4 + 3) * 1024);
                acc[g * 4 + 0] = __builtin_amdgcn_mfma_f32_16x16x32_f16(w0, t, acc[g * 4 + 0], 0, 0, 0);
                acc[g * 4 + 1] = __builtin_amdgcn_mfma_f32_16x16x32_f16(w1, t, acc[g * 4 + 1], 0, 0, 0);
                acc[g * 4 + 2] = __builtin_amdgcn_mfma_f32_16x16x32_f16(w2, t, acc[g * 4 + 2], 0, 0, 0);
                acc[g * 4 + 3] = __builtin_amdgcn_mfma_f32_16x16x32_f16(w3, t, acc[g * 4 + 3], 0, 0, 0);
            }
            // counted wait: retire the slab needed next; newest slab stays in flight
            if (more)          asm volatile("s_waitcnt vmcnt(4)" ::: "memory");
            else if (kb == 6)  asm volatile("s_waitcnt vmcnt(0)" ::: "memory");
            __builtin_amdgcn_s_barrier();
            asm volatile("" ::: "memory");
            bufc = (bufc == 2) ? 0 : bufc + 1;
            if (more) bufs = (bufs == 2) ? 0 : bufs + 1;
        }

        // ---- priors early-issue: fly during the stats phase ----
        const float* pr = priors + (size_t)myrow * D;
        f32x4 p[16];
#pragma unroll
        for (int ct = 0; ct < 16; ++ct)
            p[ct] = *reinterpret_cast<const f32x4*>(pr + ct * 16 + q * 4);

        // ---- Ghost BN stats (DPP rsum16 per strip; cross-wave via LDS) ----
#pragma unroll
        for (int ct = 0; ct < 16; ++ct) {
            f32x4 s = acc[ct];
            f32x4 qv = s * s;
#pragma unroll
            for (int c = 0; c < 4; ++c) { s[c] = rsum16(s[c]); qv[c] = rsum16(qv[c]); }
            if (lrow == 0) {
                *reinterpret_cast<f32x4*>(&sSum[wid * D + ct * 16 + q * 4]) = s;
                *reinterpret_cast<f32x4*>(&sSq [wid * D + ct * 16 + q * 4]) = qv;
            }
        }
        asm volatile("s_waitcnt lgkmcnt(0)" ::: "memory");   // ds_writes done
        __builtin_amdgcn_s_barrier();
        asm volatile("" ::: "memory");
        if (tid < D) {
            float s = 0.f, qq = 0.f;
#pragma unroll
            for (int w = 0; w < 8; ++w) { s += sSum[w * D + tid]; qq += sSq[w * D + tid]; }
            float mean = s * (1.0f / 128.0f);
            float var  = qq * (1.0f / 128.0f) - mean * mean;
            float g    = gamma[tid] * rsqrtf(var + BN_EPS);
            sA[tid] = g;
            sB[tid] = beta[tid] - mean * g;
        }
        asm volatile("s_waitcnt lgkmcnt(0)" ::: "memory");
        __builtin_amdgcn_s_barrier();
        asm volatile("" ::: "memory");

        // ---- epilogue: BN apply, * priors, sparsemax (one row per lrow-lane) ----
        float m = -1e30f;
#pragma unroll
        for (int ct = 0; ct < 16; ++ct) {
            int cc = ct * 16 + q * 4;
            f32x4 ga = *reinterpret_cast<const f32x4*>(&sA[cc]);
            f32x4 bb = *reinterpret_cast<const f32x4*>(&sB[cc]);
            f32x4 x  = (acc[ct] * ga + bb) * p[ct];
            acc[ct] = x;
            m = fmaxf(m, fmaxf(fmaxf(x[0], x[1]), fmaxf(x[2], x[3])));
        }
        m = fmaxf(m, __shfl_xor(m, 16));
        m = fmaxf(m, __shfl_xor(m, 32));

        // Michelot fixed-point from tau0 = m-1 (monotone to the exact root).
        float tau = m - 1.0f;
#pragma unroll 1
        for (int itr = 0; itr < 32; ++itr) {
            float s = 0.f, c = 0.f;
#pragma unroll
            for (int ct = 0; ct < 16; ++ct)
#pragma unroll
                for (int k = 0; k < 4; ++k) {
                    float zz = acc[ct][k];
                    if (zz > tau) { s += zz; c += 1.f; }
                }
            s += __shfl_xor(s, 16); c += __shfl_xor(c, 16);
            s += __shfl_xor(s, 32); c += __shfl_xor(c, 32);
            float n = (s - 1.0f) / c;
            bool done = (n <= tau);
            tau = fmaxf(tau, n);
            if (__all(done)) break;
        }

        float* ob = out + (size_t)myrow * D;
#pragma unroll
        for (int ct = 0; ct < 16; ++ct) {
            int cc = ct * 16 + q * 4;
            f32x4 x = acc[ct];
            f32x4 r;
#pragma unroll
            for (int k = 0; k < 4; ++k) r[k] = fmaxf(x[k] - tau, 0.f);
            *reinterpret_cast<f32x4*>(&ob[cc]) = r;
        }

        aA = aN;
    }
#undef STAGE_WK
#undef STAGE_AK
}

extern "C" void kernel_launch(void* const* d_in, const int* in_sizes, int n_in,
                              void* d_out, int out_size, void* d_ws, size_t ws_size,
                              hipStream_t stream) {
    const float* a      = (const float*)d_in[0];
    const float* priors = (const float*)d_in[1];
    const float* W      = (const float*)d_in[2];
    // d_in[3] = b : unused — ghost-BN mean subtraction cancels any per-column bias.
    const float* gamma  = (const float*)d_in[4];
    const float* beta   = (const float*)d_in[5];
    float* out = (float*)d_out;
    _Float16* wp = (_Float16*)d_ws;   // 256*256 f16 = 128 KB packed W

    const int B = in_sizes[0] / D;        // 262144
    const int nchunks = B / VBS;          // 2048

    hipLaunchKernelGGL(pack_w_kernel, dim3(32), dim3(256), 0, stream, W, wp);

    int grid = 256, iters = nchunks / 256;
    if (nchunks % 256 != 0) { grid = nchunks; iters = 1; }   // robustness fallback
    hipLaunchKernelGGL(fused_kernel, dim3(grid), dim3(512), 0, stream,
                       a, priors, wp, gamma, beta, out, iters);
}